// Round 3
// baseline (796.437 us; speedup 1.0000x reference)
//
#include <hip/hip_runtime.h>
#include <math.h>

#define D_IN 512
#define F1   16
#define F2   7

#define BKT_SHIFT 8                 // 256 nodes per bucket
#define PK_SHIFT  18                // packed word: src | (dst&255)<<18  (needs n <= 2^18)
#define PK_MASK   ((1u << PK_SHIFT) - 1u)
#define A_CHUNK   8192              // edges per workgroup in binning passes
#define B_CAP     16384             // LDS staging capacity in CSR pass (2x mean bucket size)

typedef float vf4 __attribute__((ext_vector_type(4)));  // clang vector: nontemporal-load OK

// ---- pass A1: per-bucket edge histogram (LDS-aggregated) ----
__global__ __launch_bounds__(256) void binhist_kernel(const int* __restrict__ dst,
                                                      int* __restrict__ bucket_cnt,
                                                      int E, int NB) {
    __shared__ int lh[512];
    for (int i = threadIdx.x; i < 512; i += 256) lh[i] = 0;
    __syncthreads();
    int base = blockIdx.x * A_CHUNK;
#pragma unroll
    for (int i = 0; i < A_CHUNK / 256; ++i) {
        int t = base + i * 256 + threadIdx.x;
        if (t < E) {
            int d = __builtin_nontemporal_load(&dst[t]);
            atomicAdd(&lh[d >> BKT_SHIFT], 1);
        }
    }
    __syncthreads();
    for (int i = threadIdx.x; i < NB; i += 256) {
        int v = lh[i];
        if (v) atomicAdd(&bucket_cnt[i], v);
    }
}

// ---- bucket scan: exclusive scan of bucket_cnt -> bucket_base, init bucket_cursor ----
__global__ __launch_bounds__(512) void bucketscan_kernel(const int* __restrict__ bucket_cnt,
                                                         int* __restrict__ bucket_base,
                                                         int* __restrict__ bucket_cursor,
                                                         int NB, int E) {
    __shared__ int sm[512];
    int tid = threadIdx.x;
    int v = (tid < NB) ? bucket_cnt[tid] : 0;
    sm[tid] = v;
    __syncthreads();
    for (int off = 1; off < 512; off <<= 1) {
        int t = (tid >= off) ? sm[tid - off] : 0;
        __syncthreads();
        sm[tid] += t;
        __syncthreads();
    }
    if (tid < NB) {
        int ex = sm[tid] - v;
        bucket_base[tid] = ex;
        bucket_cursor[tid] = ex;
    }
    if (tid == 0) bucket_base[NB] = E;
}

// ---- pass A2: bin edges into bucket regions with segment-contiguous writes ----
__global__ __launch_bounds__(256) void bin_kernel(const int* __restrict__ src,
                                                  const int* __restrict__ dst,
                                                  int* __restrict__ bucket_cursor,
                                                  unsigned int* __restrict__ binned,
                                                  int E, int NB) {
    __shared__ int lh[512];       // local bucket hist
    __shared__ int lbase[512];    // local exclusive scan
    __shared__ int lcur[512];     // local alloc cursor
    __shared__ int sdelta[512];   // global_seg_base - lbase
    __shared__ int sA[512], sB[512];
    __shared__ unsigned int rbuf[A_CHUNK];
    __shared__ int rdelta[A_CHUNK];
    int tid = threadIdx.x;
    for (int i = tid; i < 512; i += 256) lh[i] = 0;
    __syncthreads();

    int base = blockIdx.x * A_CHUNK;
    int dcache[A_CHUNK / 256];
    int scache[A_CHUNK / 256];
#pragma unroll
    for (int i = 0; i < A_CHUNK / 256; ++i) {
        int t = base + i * 256 + tid;
        int d = -1, s = 0;
        if (t < E) {
            d = __builtin_nontemporal_load(&dst[t]);
            s = __builtin_nontemporal_load(&src[t]);
            atomicAdd(&lh[d >> BKT_SHIFT], 1);
        }
        dcache[i] = d;
        scache[i] = s;
    }
    __syncthreads();

    // scan lh (512 entries, ping-pong Hillis-Steele) -> inclusive in psrc
    for (int i = tid; i < 512; i += 256) sA[i] = lh[i];
    __syncthreads();
    int* psrc = sA; int* pdst = sB;
    for (int off = 1; off < 512; off <<= 1) {
        for (int i = tid; i < 512; i += 256)
            pdst[i] = psrc[i] + ((i >= off) ? psrc[i - off] : 0);
        __syncthreads();
        int* tmp = psrc; psrc = pdst; pdst = tmp;
    }
    for (int i = tid; i < 512; i += 256) {
        int ex = psrc[i] - lh[i];
        lbase[i] = ex;
        lcur[i] = ex;
    }
    __syncthreads();

    // reserve one global segment per bucket for this chunk
    for (int b = tid; b < NB; b += 256) {
        int c = lh[b];
        int g = c ? atomicAdd(&bucket_cursor[b], c) : 0;
        sdelta[b] = g - lbase[b];
    }
    __syncthreads();

    // local reorder into rbuf
#pragma unroll
    for (int i = 0; i < A_CHUNK / 256; ++i) {
        int d = dcache[i];
        if (d >= 0) {
            int b = d >> BKT_SHIFT;
            int p = atomicAdd(&lcur[b], 1);
            rbuf[p] = (unsigned int)scache[i] | ((unsigned int)(d & 255) << PK_SHIFT);
            rdelta[p] = sdelta[b];
        }
    }
    __syncthreads();

    // write out: positions p within a segment map to consecutive global addresses
    int total = min(A_CHUNK, E - base);
    for (int p = tid; p < total; p += 256)
        binned[rdelta[p] + p] = rbuf[p];
}

// ---- pass B: per-bucket local counting sort -> adj, row_ptr/row_end/dinv ----
__global__ __launch_bounds__(256) void csr_kernel(const unsigned int* __restrict__ binned,
                                                  const int* __restrict__ bucket_base,
                                                  int* __restrict__ row_ptr,
                                                  int* __restrict__ row_end,
                                                  float* __restrict__ dinv,
                                                  int* __restrict__ adj, int n) {
    __shared__ int lh[256], lscan[256], lcur[256];
    __shared__ unsigned int rbuf[B_CAP];
    int b = blockIdx.x;
    int tid = threadIdx.x;
    int gbase = bucket_base[b];
    int gend  = bucket_base[b + 1];
    int m = gend - gbase;
    lh[tid] = 0;
    __syncthreads();
    // hist + LDS stage (nt loads: streaming, don't evict adj dirty lines)
    for (int i = tid; i < m; i += 256) {
        unsigned int w = __builtin_nontemporal_load(&binned[gbase + i]);
        if (i < B_CAP) rbuf[i] = w;
        atomicAdd(&lh[w >> PK_SHIFT], 1);
    }
    __syncthreads();
    // 256-entry Hillis-Steele scan
    int v = lh[tid];
    lscan[tid] = v;
    __syncthreads();
    for (int off = 1; off < 256; off <<= 1) {
        int t = (tid >= off) ? lscan[tid - off] : 0;
        __syncthreads();
        lscan[tid] += t;
        __syncthreads();
    }
    int ex = lscan[tid] - v;  // exclusive
    int node = (b << BKT_SHIFT) + tid;
    if (node < n) {
        row_ptr[node] = gbase + ex;
        row_end[node] = gbase + ex + v;
        dinv[node] = rsqrtf((float)v + 1.0f);
    }
    lcur[tid] = ex;
    __syncthreads();
    // scatter into this bucket's private 32KB adj window (L2 merges the fills)
    for (int i = tid; i < m; i += 256) {
        unsigned int w = (i < B_CAP) ? rbuf[i] : binned[gbase + i];
        int d = (int)(w >> PK_SHIFT);
        int s = (int)(w & PK_MASK);
        int p = atomicAdd(&lcur[d], 1);
        adj[gbase + p] = s;
    }
}

// ---- layer-1 matmul: h1s = (x @ W1) * dinv[node], 8-lanes-per-node, no LDS ----
// Wave = 8 nodes x 8 lanes. Per iteration i, lane (node m, sub) loads the float4
// at x[node][i*32 + sub*4]: the 8 subs of a node cover one contiguous 128B
// segment, so every fetched line is fully consumed by the SAME instruction ->
// over-fetch is structurally 1.0x, no L1 reuse needed, no LDS, no barriers, no
// registers live across syncs (the round-2 spill). Partials: acc[16] over this
// lane's 64 K-elems; 3-stage __shfl_xor(.,8) butterfly sums the 8 lanes; lanes
// sub<4 each store one float4 quarter (selected by constant-index cndmask chain
// -- rule #20: no runtime-indexed register arrays).
__global__ __launch_bounds__(256) void mm1_kernel(const float* __restrict__ x,
                                                  const float* __restrict__ W1,
                                                  const float* __restrict__ dinv,
                                                  float* __restrict__ h1s, int n) {
    int tid = threadIdx.x;
    int l   = tid & 63;
    int wv  = tid >> 6;
    int sub = l & 7;
    int node = blockIdx.x * 32 + wv * 8 + (l >> 3);
    int gn = node < n ? node : n - 1;

    const vf4* xp = (const vf4*)(x + (size_t)gn * D_IN);
    float acc[F1];
#pragma unroll
    for (int j = 0; j < F1; ++j) acc[j] = 0.0f;

#pragma unroll
    for (int i = 0; i < 16; ++i) {
        vf4 xq = __builtin_nontemporal_load(xp + i * 8 + sub);
        const float4* wr = (const float4*)(W1 + (size_t)(i * 32 + sub * 4) * F1);
#pragma unroll
        for (int kk = 0; kk < 4; ++kk) {
            float xe = xq[kk];
            float4 w0 = wr[kk * 4 + 0], w1 = wr[kk * 4 + 1];
            float4 w2 = wr[kk * 4 + 2], w3 = wr[kk * 4 + 3];
            acc[ 0] += xe * w0.x; acc[ 1] += xe * w0.y; acc[ 2] += xe * w0.z; acc[ 3] += xe * w0.w;
            acc[ 4] += xe * w1.x; acc[ 5] += xe * w1.y; acc[ 6] += xe * w1.z; acc[ 7] += xe * w1.w;
            acc[ 8] += xe * w2.x; acc[ 9] += xe * w2.y; acc[10] += xe * w2.z; acc[11] += xe * w2.w;
            acc[12] += xe * w3.x; acc[13] += xe * w3.y; acc[14] += xe * w3.z; acc[15] += xe * w3.w;
        }
    }

    // butterfly-sum over the 8 subs (low 3 lane bits)
#pragma unroll
    for (int j = 0; j < F1; ++j) {
        acc[j] += __shfl_xor(acc[j], 1, 8);
        acc[j] += __shfl_xor(acc[j], 2, 8);
        acc[j] += __shfl_xor(acc[j], 4, 8);
    }

    if (node < n && sub < 4) {
        // lane sub writes feature quarter sub: constant indices only
        float q0 = sub == 0 ? acc[0] : sub == 1 ? acc[4] : sub == 2 ? acc[ 8] : acc[12];
        float q1 = sub == 0 ? acc[1] : sub == 1 ? acc[5] : sub == 2 ? acc[ 9] : acc[13];
        float q2 = sub == 0 ? acc[2] : sub == 1 ? acc[6] : sub == 2 ? acc[10] : acc[14];
        float q3 = sub == 0 ? acc[3] : sub == 1 ? acc[7] : sub == 2 ? acc[11] : acc[15];
        float di = dinv[node];
        *((float4*)(h1s + (size_t)node * F1 + sub * 4)) =
            make_float4(q0 * di, q1 * di, q2 * di, q3 * di);
    }
}

// ---- layer-1 gather + fused finalize: acc1 = relu(dinv*(sum + h1s[node]) + b1) ----
__global__ __launch_bounds__(256) void agg1_kernel(const int* __restrict__ row_ptr,
                                                   const int* __restrict__ row_end,
                                                   const int* __restrict__ adj,
                                                   const float* __restrict__ h,
                                                   const float* __restrict__ dinv,
                                                   const float* __restrict__ b1,
                                                   float* __restrict__ acc, int n) {
    int t = blockIdx.x * 256 + threadIdx.x;
    int node = t >> 4, j = t & 15;
    if (node >= n) return;
    int s = row_ptr[node], e = row_end[node];
    float a0 = 0.0f, a1 = 0.0f;
    int k = s;
    for (; k + 1 < e; k += 2) {
        int s0 = adj[k], s1 = adj[k + 1];
        a0 += h[(size_t)s0 * F1 + j];
        a1 += h[(size_t)s1 * F1 + j];
    }
    if (k < e) a0 += h[(size_t)adj[k] * F1 + j];
    float di = dinv[node];
    float v = di * (a0 + a1 + h[(size_t)node * F1 + j]) + b1[j];
    acc[(size_t)node * F1 + j] = v > 0.0f ? v : 0.0f;
}

// ---------------- layer-2 matmul: h2s = (h @ W2) * dinv, padded stride 8 ----------------
__global__ __launch_bounds__(256) void mm2_kernel(const float* __restrict__ hin,
                                                  const float* __restrict__ W2,
                                                  const float* __restrict__ dinv,
                                                  float* __restrict__ h2s, int n) {
    int t = blockIdx.x * blockDim.x + threadIdx.x;
    if (t >= n) return;
    const float4* hr = (const float4*)(hin + (size_t)t * F1);
    float hv[F1];
#pragma unroll
    for (int q = 0; q < 4; ++q) {
        float4 v = hr[q];
        hv[4 * q + 0] = v.x; hv[4 * q + 1] = v.y;
        hv[4 * q + 2] = v.z; hv[4 * q + 3] = v.w;
    }
    float acc[F2];
#pragma unroll
    for (int j = 0; j < F2; ++j) acc[j] = 0.0f;
#pragma unroll
    for (int k = 0; k < F1; ++k) {
        float xv = hv[k];
#pragma unroll
        for (int j = 0; j < F2; ++j) acc[j] += xv * W2[k * F2 + j];
    }
    float di = dinv[t];
    float* outp = h2s + (size_t)t * 8;
#pragma unroll
    for (int j = 0; j < F2; ++j) outp[j] = acc[j] * di;
    outp[7] = 0.0f;
}

// ---- layer-2 gather + fused bias/self-loop/log_softmax -> out (stride 7) ----
__global__ __launch_bounds__(256) void agg2_kernel(const int* __restrict__ row_ptr,
                                                   const int* __restrict__ row_end,
                                                   const int* __restrict__ adj,
                                                   const float* __restrict__ h,
                                                   const float* __restrict__ dinv,
                                                   const float* __restrict__ b2,
                                                   float* __restrict__ out, int n) {
    int t = blockIdx.x * 256 + threadIdx.x;
    int node = t >> 3, j = t & 7;
    if (node >= n) return;
    int s = row_ptr[node], e = row_end[node];
    float a0 = 0.0f, a1 = 0.0f;
    int k = s;
    for (; k + 1 < e; k += 2) {
        int s0 = adj[k], s1 = adj[k + 1];
        a0 += h[(size_t)s0 * 8 + j];
        a1 += h[(size_t)s1 * 8 + j];
    }
    if (k < e) a0 += h[(size_t)adj[k] * 8 + j];
    float di = dinv[node];
    float bj = j < F2 ? b2[j] : 0.0f;
    float v = di * (a0 + a1 + h[(size_t)node * 8 + j]) + bj;
    if (j >= F2) v = -INFINITY;   // pad lane: never the max, exp()=0
    float m = v;
#pragma unroll
    for (int w = 1; w < 8; w <<= 1) m = fmaxf(m, __shfl_xor(m, w, 8));
    float ex = (j < F2) ? expf(v - m) : 0.0f;
    float sum = ex;
#pragma unroll
    for (int w = 1; w < 8; w <<= 1) sum += __shfl_xor(sum, w, 8);
    float lse = m + logf(sum);
    if (j < F2) out[(size_t)node * F2 + j] = v - lse;
}

extern "C" void kernel_launch(void* const* d_in, const int* in_sizes, int n_in,
                              void* d_out, int out_size, void* d_ws, size_t ws_size,
                              hipStream_t stream) {
    const float* x  = (const float*)d_in[0];
    const int*   ei = (const int*)d_in[1];
    const float* W1 = (const float*)d_in[2];
    const float* b1 = (const float*)d_in[3];
    const float* W2 = (const float*)d_in[4];
    const float* b2 = (const float*)d_in[5];

    int n = in_sizes[0] / D_IN;
    int E = in_sizes[1] / 2;
    const int* src = ei;
    const int* dst = ei + E;
    int NB = (n + 255) >> BKT_SHIFT;   // buckets (<=512 for n<=131072)

    // workspace layout (4-byte elements); binned aliases h1s/acc1 (dead before mm1)
    char* ws = (char*)d_ws;
    size_t o = 0;
    int* bucket_cnt    = (int*)(ws + o); o += 512 * 4;
    int* bucket_base   = (int*)(ws + o); o += 516 * 4;
    int* bucket_cursor = (int*)(ws + o); o += 512 * 4;
    int*   row_ptr = (int*)(ws + o);   o += (size_t)n * 4;
    int*   row_end = (int*)(ws + o);   o += (size_t)n * 4;
    float* dinv    = (float*)(ws + o); o += (size_t)n * 4;
    int*   adj     = (int*)(ws + o);   o += (size_t)E * 4;
    size_t uni = (size_t)E > (size_t)n * 32 ? (size_t)E : (size_t)n * 32;
    unsigned int* binned = (unsigned int*)(ws + o);
    float* h1s  = (float*)(ws + o);                    // overwrites binned after csr pass
    float* acc1 = (float*)(ws + o) + (size_t)n * F1;
    o += uni * 4;
    float* h2s = h1s;  // mm2 reads acc1, writes h2s (h1s dead after agg1)
    float* out = (float*)d_out;

    const int B = 256;
    int GA = (E + A_CHUNK - 1) / A_CHUNK;
    int gN = (n + B - 1) / B;

    hipMemsetAsync(bucket_cnt, 0, 512 * sizeof(int), stream);

    binhist_kernel<<<GA, B, 0, stream>>>(dst, bucket_cnt, E, NB);
    bucketscan_kernel<<<1, 512, 0, stream>>>(bucket_cnt, bucket_base, bucket_cursor, NB, E);
    bin_kernel<<<GA, B, 0, stream>>>(src, dst, bucket_cursor, binned, E, NB);
    csr_kernel<<<NB, B, 0, stream>>>(binned, bucket_base, row_ptr, row_end, dinv, adj, n);

    mm1_kernel<<<(n + 31) / 32, B, 0, stream>>>(x, W1, dinv, h1s, n);

    agg1_kernel<<<((size_t)n * F1 + B - 1) / B, B, 0, stream>>>(row_ptr, row_end, adj, h1s, dinv, b1, acc1, n);

    mm2_kernel<<<gN, B, 0, stream>>>(acc1, W2, dinv, h2s, n);

    agg2_kernel<<<((size_t)n * 8 + B - 1) / B, B, 0, stream>>>(row_ptr, row_end, adj, h2s, dinv, b2, out, n);
}

// Round 4
// 500.861 us; speedup vs baseline: 1.5901x; 1.5901x over previous
//
#include <hip/hip_runtime.h>
#include <math.h>

#define D_IN 512
#define F1   16
#define F2   7

#define BKT_SHIFT 8                 // 256 nodes per bucket
#define PK_SHIFT  18                // packed word: src | (dst&255)<<18  (needs n <= 2^18)
#define PK_MASK   ((1u << PK_SHIFT) - 1u)
#define A_CHUNK   8192              // edges per workgroup in binning passes
#define B_CAP     16384             // LDS staging capacity in CSR pass (2x mean bucket size)

typedef float vf4 __attribute__((ext_vector_type(4)));  // clang vector: nontemporal-load OK

// ---- pass A1: per-bucket edge histogram (LDS-aggregated) ----
__global__ __launch_bounds__(256) void binhist_kernel(const int* __restrict__ dst,
                                                      int* __restrict__ bucket_cnt,
                                                      int E, int NB) {
    __shared__ int lh[512];
    for (int i = threadIdx.x; i < 512; i += 256) lh[i] = 0;
    __syncthreads();
    int base = blockIdx.x * A_CHUNK;
#pragma unroll
    for (int i = 0; i < A_CHUNK / 256; ++i) {
        int t = base + i * 256 + threadIdx.x;
        if (t < E) {
            int d = __builtin_nontemporal_load(&dst[t]);
            atomicAdd(&lh[d >> BKT_SHIFT], 1);
        }
    }
    __syncthreads();
    for (int i = threadIdx.x; i < NB; i += 256) {
        int v = lh[i];
        if (v) atomicAdd(&bucket_cnt[i], v);
    }
}

// ---- bucket scan: exclusive scan of bucket_cnt -> bucket_base, init bucket_cursor ----
__global__ __launch_bounds__(512) void bucketscan_kernel(const int* __restrict__ bucket_cnt,
                                                         int* __restrict__ bucket_base,
                                                         int* __restrict__ bucket_cursor,
                                                         int NB, int E) {
    __shared__ int sm[512];
    int tid = threadIdx.x;
    int v = (tid < NB) ? bucket_cnt[tid] : 0;
    sm[tid] = v;
    __syncthreads();
    for (int off = 1; off < 512; off <<= 1) {
        int t = (tid >= off) ? sm[tid - off] : 0;
        __syncthreads();
        sm[tid] += t;
        __syncthreads();
    }
    if (tid < NB) {
        int ex = sm[tid] - v;
        bucket_base[tid] = ex;
        bucket_cursor[tid] = ex;
    }
    if (tid == 0) bucket_base[NB] = E;
}

// ---- pass A2: bin edges into bucket regions with segment-contiguous writes ----
__global__ __launch_bounds__(256) void bin_kernel(const int* __restrict__ src,
                                                  const int* __restrict__ dst,
                                                  int* __restrict__ bucket_cursor,
                                                  unsigned int* __restrict__ binned,
                                                  int E, int NB) {
    __shared__ int lh[512];       // local bucket hist
    __shared__ int lbase[512];    // local exclusive scan
    __shared__ int lcur[512];     // local alloc cursor
    __shared__ int sdelta[512];   // global_seg_base - lbase
    __shared__ int sA[512], sB[512];
    __shared__ unsigned int rbuf[A_CHUNK];
    __shared__ int rdelta[A_CHUNK];
    int tid = threadIdx.x;
    for (int i = tid; i < 512; i += 256) lh[i] = 0;
    __syncthreads();

    int base = blockIdx.x * A_CHUNK;
    int dcache[A_CHUNK / 256];
    int scache[A_CHUNK / 256];
#pragma unroll
    for (int i = 0; i < A_CHUNK / 256; ++i) {
        int t = base + i * 256 + tid;
        int d = -1, s = 0;
        if (t < E) {
            d = __builtin_nontemporal_load(&dst[t]);
            s = __builtin_nontemporal_load(&src[t]);
            atomicAdd(&lh[d >> BKT_SHIFT], 1);
        }
        dcache[i] = d;
        scache[i] = s;
    }
    __syncthreads();

    // scan lh (512 entries, ping-pong Hillis-Steele) -> inclusive in psrc
    for (int i = tid; i < 512; i += 256) sA[i] = lh[i];
    __syncthreads();
    int* psrc = sA; int* pdst = sB;
    for (int off = 1; off < 512; off <<= 1) {
        for (int i = tid; i < 512; i += 256)
            pdst[i] = psrc[i] + ((i >= off) ? psrc[i - off] : 0);
        __syncthreads();
        int* tmp = psrc; psrc = pdst; pdst = tmp;
    }
    for (int i = tid; i < 512; i += 256) {
        int ex = psrc[i] - lh[i];
        lbase[i] = ex;
        lcur[i] = ex;
    }
    __syncthreads();

    // reserve one global segment per bucket for this chunk
    for (int b = tid; b < NB; b += 256) {
        int c = lh[b];
        int g = c ? atomicAdd(&bucket_cursor[b], c) : 0;
        sdelta[b] = g - lbase[b];
    }
    __syncthreads();

    // local reorder into rbuf
#pragma unroll
    for (int i = 0; i < A_CHUNK / 256; ++i) {
        int d = dcache[i];
        if (d >= 0) {
            int b = d >> BKT_SHIFT;
            int p = atomicAdd(&lcur[b], 1);
            rbuf[p] = (unsigned int)scache[i] | ((unsigned int)(d & 255) << PK_SHIFT);
            rdelta[p] = sdelta[b];
        }
    }
    __syncthreads();

    // write out: positions p within a segment map to consecutive global addresses
    int total = min(A_CHUNK, E - base);
    for (int p = tid; p < total; p += 256)
        binned[rdelta[p] + p] = rbuf[p];
}

// ---- pass B: per-bucket local counting sort -> adj, row_ptr/row_end/dinv ----
__global__ __launch_bounds__(256) void csr_kernel(const unsigned int* __restrict__ binned,
                                                  const int* __restrict__ bucket_base,
                                                  int* __restrict__ row_ptr,
                                                  int* __restrict__ row_end,
                                                  float* __restrict__ dinv,
                                                  int* __restrict__ adj, int n) {
    __shared__ int lh[256], lscan[256], lcur[256];
    __shared__ unsigned int rbuf[B_CAP];
    int b = blockIdx.x;
    int tid = threadIdx.x;
    int gbase = bucket_base[b];
    int gend  = bucket_base[b + 1];
    int m = gend - gbase;
    lh[tid] = 0;
    __syncthreads();
    // hist + LDS stage (nt loads: streaming, don't evict adj dirty lines)
    for (int i = tid; i < m; i += 256) {
        unsigned int w = __builtin_nontemporal_load(&binned[gbase + i]);
        if (i < B_CAP) rbuf[i] = w;
        atomicAdd(&lh[w >> PK_SHIFT], 1);
    }
    __syncthreads();
    // 256-entry Hillis-Steele scan
    int v = lh[tid];
    lscan[tid] = v;
    __syncthreads();
    for (int off = 1; off < 256; off <<= 1) {
        int t = (tid >= off) ? lscan[tid - off] : 0;
        __syncthreads();
        lscan[tid] += t;
        __syncthreads();
    }
    int ex = lscan[tid] - v;  // exclusive
    int node = (b << BKT_SHIFT) + tid;
    if (node < n) {
        row_ptr[node] = gbase + ex;
        row_end[node] = gbase + ex + v;
        dinv[node] = rsqrtf((float)v + 1.0f);
    }
    lcur[tid] = ex;
    __syncthreads();
    // scatter into this bucket's private 32KB adj window (L2 merges the fills)
    for (int i = tid; i < m; i += 256) {
        unsigned int w = (i < B_CAP) ? rbuf[i] : binned[gbase + i];
        int d = (int)(w >> PK_SHIFT);
        int s = (int)(w & PK_MASK);
        int p = atomicAdd(&lcur[d], 1);
        adj[gbase + p] = s;
    }
}

// ---- layer-1 matmul: h1s = (x @ W1) * dinv[node] ----
// One wave = one node per iteration. Lane l owns the fixed K-slice
// {4l..4l+3} u {256+4l..256+4l+3}; its 8 W1 rows (128 floats) are preloaded
// ONCE into VGPRs and reused for every node (round-3 defect: 256 W1 loads per
// lane per 8 nodes -> latency-bound at 290 GB/s). Per node: two fully-dense
// dwordx4 loads cover the whole 2KB x row (over-fetch 1.0x), 128 register-only
// FMAs, then a feature-splitting butterfly (17 shuffles) leaves feature f in
// lane f. Next node's row is prefetched into regs before the FMA phase (T14).
// No LDS, no barriers, nothing live across syncs. ~185 VGPR -> 2 waves/SIMD;
// grid 512 blocks = 2048 waves = 8/CU.
__global__ __launch_bounds__(256, 2) void mm1_kernel(const float* __restrict__ x,
                                                     const float* __restrict__ W1,
                                                     const float* __restrict__ dinv,
                                                     float* __restrict__ h1s, int n) {
    int tid = threadIdx.x;
    int lane = tid & 63;
    int wid  = blockIdx.x * 4 + (tid >> 6);   // global wave id
    int nwaves = gridDim.x * 4;

    // preload W1 rows kA = 4*lane + r and kB = 256 + 4*lane + r (r=0..3)
    float wA[4][16], wB[4][16];
#pragma unroll
    for (int r = 0; r < 4; ++r) {
        const float4* ra = (const float4*)(W1 + (size_t)(4 * lane + r) * F1);
        const float4* rb = (const float4*)(W1 + (size_t)(256 + 4 * lane + r) * F1);
#pragma unroll
        for (int q = 0; q < 4; ++q) {
            float4 va = ra[q], vb = rb[q];
            wA[r][4 * q + 0] = va.x; wA[r][4 * q + 1] = va.y;
            wA[r][4 * q + 2] = va.z; wA[r][4 * q + 3] = va.w;
            wB[r][4 * q + 0] = vb.x; wB[r][4 * q + 1] = vb.y;
            wB[r][4 * q + 2] = vb.z; wB[r][4 * q + 3] = vb.w;
        }
    }

    int node = wid;
    if (node >= n) return;
    const float* xb = x + (size_t)node * D_IN;
    vf4 pA = *(const vf4*)(xb + 4 * lane);          // k = 4l..4l+3
    vf4 pB = *(const vf4*)(xb + 256 + 4 * lane);    // k = 256+4l..+3

    while (node < n) {
        vf4 xA = pA, xB = pB;
        int nx = node + nwaves;
        if (nx < n) {                                // prefetch next row (wave-uniform branch)
            const float* xn = x + (size_t)nx * D_IN;
            pA = *(const vf4*)(xn + 4 * lane);
            pB = *(const vf4*)(xn + 256 + 4 * lane);
        }
        float acc[16];
#pragma unroll
        for (int f = 0; f < 16; ++f) acc[f] = 0.f;
#pragma unroll
        for (int r = 0; r < 4; ++r) {
            float ea = xA[r], eb = xB[r];
#pragma unroll
            for (int f = 0; f < 16; ++f) {
                acc[f] += ea * wA[r][f];
                acc[f] += eb * wB[r][f];
            }
        }
        // butterfly: stage s splits features by bit s == lane bit s -> lane f holds feature f
        int h0 = lane & 1, h1 = lane & 2, h2 = lane & 4, h3 = lane & 8;
        float a[8];
#pragma unroll
        for (int j = 0; j < 8; ++j) {
            float keep = h0 ? acc[2 * j + 1] : acc[2 * j];
            float give = h0 ? acc[2 * j] : acc[2 * j + 1];
            a[j] = keep + __shfl_xor(give, 1);
        }
        float b[4];
#pragma unroll
        for (int j = 0; j < 4; ++j) {
            float keep = h1 ? a[2 * j + 1] : a[2 * j];
            float give = h1 ? a[2 * j] : a[2 * j + 1];
            b[j] = keep + __shfl_xor(give, 2);
        }
        float c[2];
#pragma unroll
        for (int j = 0; j < 2; ++j) {
            float keep = h2 ? b[2 * j + 1] : b[2 * j];
            float give = h2 ? b[2 * j] : b[2 * j + 1];
            c[j] = keep + __shfl_xor(give, 4);
        }
        float d = (h3 ? c[1] : c[0]) + __shfl_xor(h3 ? c[0] : c[1], 8);
        d += __shfl_xor(d, 16);
        d += __shfl_xor(d, 32);
        if (lane < 16) {
            float di = dinv[node];
            h1s[(size_t)node * F1 + lane] = d * di;   // 64B contiguous store
        }
        node = nx;
    }
}

// ---- layer-1 gather + fused finalize: acc1 = relu(dinv*(sum + h1s[node]) + b1) ----
__global__ __launch_bounds__(256) void agg1_kernel(const int* __restrict__ row_ptr,
                                                   const int* __restrict__ row_end,
                                                   const int* __restrict__ adj,
                                                   const float* __restrict__ h,
                                                   const float* __restrict__ dinv,
                                                   const float* __restrict__ b1,
                                                   float* __restrict__ acc, int n) {
    int t = blockIdx.x * 256 + threadIdx.x;
    int node = t >> 4, j = t & 15;
    if (node >= n) return;
    int s = row_ptr[node], e = row_end[node];
    float a0 = 0.0f, a1 = 0.0f;
    int k = s;
    for (; k + 1 < e; k += 2) {
        int s0 = adj[k], s1 = adj[k + 1];
        a0 += h[(size_t)s0 * F1 + j];
        a1 += h[(size_t)s1 * F1 + j];
    }
    if (k < e) a0 += h[(size_t)adj[k] * F1 + j];
    float di = dinv[node];
    float v = di * (a0 + a1 + h[(size_t)node * F1 + j]) + b1[j];
    acc[(size_t)node * F1 + j] = v > 0.0f ? v : 0.0f;
}

// ---------------- layer-2 matmul: h2s = (h @ W2) * dinv, padded stride 8 ----------------
__global__ __launch_bounds__(256) void mm2_kernel(const float* __restrict__ hin,
                                                  const float* __restrict__ W2,
                                                  const float* __restrict__ dinv,
                                                  float* __restrict__ h2s, int n) {
    int t = blockIdx.x * blockDim.x + threadIdx.x;
    if (t >= n) return;
    const float4* hr = (const float4*)(hin + (size_t)t * F1);
    float hv[F1];
#pragma unroll
    for (int q = 0; q < 4; ++q) {
        float4 v = hr[q];
        hv[4 * q + 0] = v.x; hv[4 * q + 1] = v.y;
        hv[4 * q + 2] = v.z; hv[4 * q + 3] = v.w;
    }
    float acc[F2];
#pragma unroll
    for (int j = 0; j < F2; ++j) acc[j] = 0.0f;
#pragma unroll
    for (int k = 0; k < F1; ++k) {
        float xv = hv[k];
#pragma unroll
        for (int j = 0; j < F2; ++j) acc[j] += xv * W2[k * F2 + j];
    }
    float di = dinv[t];
    float* outp = h2s + (size_t)t * 8;
#pragma unroll
    for (int j = 0; j < F2; ++j) outp[j] = acc[j] * di;
    outp[7] = 0.0f;
}

// ---- layer-2 gather + fused bias/self-loop/log_softmax -> out (stride 7) ----
__global__ __launch_bounds__(256) void agg2_kernel(const int* __restrict__ row_ptr,
                                                   const int* __restrict__ row_end,
                                                   const int* __restrict__ adj,
                                                   const float* __restrict__ h,
                                                   const float* __restrict__ dinv,
                                                   const float* __restrict__ b2,
                                                   float* __restrict__ out, int n) {
    int t = blockIdx.x * 256 + threadIdx.x;
    int node = t >> 3, j = t & 7;
    if (node >= n) return;
    int s = row_ptr[node], e = row_end[node];
    float a0 = 0.0f, a1 = 0.0f;
    int k = s;
    for (; k + 1 < e; k += 2) {
        int s0 = adj[k], s1 = adj[k + 1];
        a0 += h[(size_t)s0 * 8 + j];
        a1 += h[(size_t)s1 * 8 + j];
    }
    if (k < e) a0 += h[(size_t)adj[k] * 8 + j];
    float di = dinv[node];
    float bj = j < F2 ? b2[j] : 0.0f;
    float v = di * (a0 + a1 + h[(size_t)node * 8 + j]) + bj;
    if (j >= F2) v = -INFINITY;   // pad lane: never the max, exp()=0
    float m = v;
#pragma unroll
    for (int w = 1; w < 8; w <<= 1) m = fmaxf(m, __shfl_xor(m, w, 8));
    float ex = (j < F2) ? expf(v - m) : 0.0f;
    float sum = ex;
#pragma unroll
    for (int w = 1; w < 8; w <<= 1) sum += __shfl_xor(sum, w, 8);
    float lse = m + logf(sum);
    if (j < F2) out[(size_t)node * F2 + j] = v - lse;
}

extern "C" void kernel_launch(void* const* d_in, const int* in_sizes, int n_in,
                              void* d_out, int out_size, void* d_ws, size_t ws_size,
                              hipStream_t stream) {
    const float* x  = (const float*)d_in[0];
    const int*   ei = (const int*)d_in[1];
    const float* W1 = (const float*)d_in[2];
    const float* b1 = (const float*)d_in[3];
    const float* W2 = (const float*)d_in[4];
    const float* b2 = (const float*)d_in[5];

    int n = in_sizes[0] / D_IN;
    int E = in_sizes[1] / 2;
    const int* src = ei;
    const int* dst = ei + E;
    int NB = (n + 255) >> BKT_SHIFT;   // buckets (<=512 for n<=131072)

    // workspace layout (4-byte elements); binned aliases h1s/acc1 (dead before mm1)
    char* ws = (char*)d_ws;
    size_t o = 0;
    int* bucket_cnt    = (int*)(ws + o); o += 512 * 4;
    int* bucket_base   = (int*)(ws + o); o += 516 * 4;
    int* bucket_cursor = (int*)(ws + o); o += 512 * 4;
    int*   row_ptr = (int*)(ws + o);   o += (size_t)n * 4;
    int*   row_end = (int*)(ws + o);   o += (size_t)n * 4;
    float* dinv    = (float*)(ws + o); o += (size_t)n * 4;
    int*   adj     = (int*)(ws + o);   o += (size_t)E * 4;
    size_t uni = (size_t)E > (size_t)n * 32 ? (size_t)E : (size_t)n * 32;
    unsigned int* binned = (unsigned int*)(ws + o);
    float* h1s  = (float*)(ws + o);                    // overwrites binned after csr pass
    float* acc1 = (float*)(ws + o) + (size_t)n * F1;
    o += uni * 4;
    float* h2s = h1s;  // mm2 reads acc1, writes h2s (h1s dead after agg1)
    float* out = (float*)d_out;

    const int B = 256;
    int GA = (E + A_CHUNK - 1) / A_CHUNK;
    int gN = (n + B - 1) / B;

    hipMemsetAsync(bucket_cnt, 0, 512 * sizeof(int), stream);

    binhist_kernel<<<GA, B, 0, stream>>>(dst, bucket_cnt, E, NB);
    bucketscan_kernel<<<1, 512, 0, stream>>>(bucket_cnt, bucket_base, bucket_cursor, NB, E);
    bin_kernel<<<GA, B, 0, stream>>>(src, dst, bucket_cursor, binned, E, NB);
    csr_kernel<<<NB, B, 0, stream>>>(binned, bucket_base, row_ptr, row_end, dinv, adj, n);

    mm1_kernel<<<512, B, 0, stream>>>(x, W1, dinv, h1s, n);

    agg1_kernel<<<((size_t)n * F1 + B - 1) / B, B, 0, stream>>>(row_ptr, row_end, adj, h1s, dinv, b1, acc1, n);

    mm2_kernel<<<gN, B, 0, stream>>>(acc1, W2, dinv, h2s, n);

    agg2_kernel<<<((size_t)n * 8 + B - 1) / B, B, 0, stream>>>(row_ptr, row_end, adj, h2s, dinv, b2, out, n);
}

// Round 6
// 471.193 us; speedup vs baseline: 1.6903x; 1.0630x over previous
//
#include <hip/hip_runtime.h>
#include <math.h>

#define D_IN 512
#define F1   16
#define F2   7

#define BKT_SHIFT 8                 // 256 nodes per bucket
#define PK_SHIFT  18                // packed word: src | (dst&255)<<18  (needs n <= 2^18)
#define PK_MASK   ((1u << PK_SHIFT) - 1u)
#define A_CHUNK   8192              // edges per workgroup in binning passes
#define B_CAP     16384             // LDS staging capacity in CSR pass (2x mean bucket size)

typedef float vf4 __attribute__((ext_vector_type(4)));  // clang vector: nontemporal-load OK

// ---- pass A1: per-bucket edge histogram (LDS-aggregated) ----
__global__ __launch_bounds__(256) void binhist_kernel(const int* __restrict__ dst,
                                                      int* __restrict__ bucket_cnt,
                                                      int E, int NB) {
    __shared__ int lh[512];
    for (int i = threadIdx.x; i < 512; i += 256) lh[i] = 0;
    __syncthreads();
    int base = blockIdx.x * A_CHUNK;
#pragma unroll
    for (int i = 0; i < A_CHUNK / 256; ++i) {
        int t = base + i * 256 + threadIdx.x;
        if (t < E) {
            int d = __builtin_nontemporal_load(&dst[t]);
            atomicAdd(&lh[d >> BKT_SHIFT], 1);
        }
    }
    __syncthreads();
    for (int i = threadIdx.x; i < NB; i += 256) {
        int v = lh[i];
        if (v) atomicAdd(&bucket_cnt[i], v);
    }
}

// ---- bucket scan: exclusive scan of bucket_cnt -> bucket_base, init bucket_cursor ----
__global__ __launch_bounds__(512) void bucketscan_kernel(const int* __restrict__ bucket_cnt,
                                                         int* __restrict__ bucket_base,
                                                         int* __restrict__ bucket_cursor,
                                                         int NB, int E) {
    __shared__ int sm[512];
    int tid = threadIdx.x;
    int v = (tid < NB) ? bucket_cnt[tid] : 0;
    sm[tid] = v;
    __syncthreads();
    for (int off = 1; off < 512; off <<= 1) {
        int t = (tid >= off) ? sm[tid - off] : 0;
        __syncthreads();
        sm[tid] += t;
        __syncthreads();
    }
    if (tid < NB) {
        int ex = sm[tid] - v;
        bucket_base[tid] = ex;
        bucket_cursor[tid] = ex;
    }
    if (tid == 0) bucket_base[NB] = E;
}

// ---- pass A2: bin edges into bucket regions with segment-contiguous writes ----
__global__ __launch_bounds__(256) void bin_kernel(const int* __restrict__ src,
                                                  const int* __restrict__ dst,
                                                  int* __restrict__ bucket_cursor,
                                                  unsigned int* __restrict__ binned,
                                                  int E, int NB) {
    __shared__ int lh[512];       // local bucket hist
    __shared__ int lbase[512];    // local exclusive scan
    __shared__ int lcur[512];     // local alloc cursor
    __shared__ int sdelta[512];   // global_seg_base - lbase
    __shared__ int sA[512], sB[512];
    __shared__ unsigned int rbuf[A_CHUNK];
    __shared__ int rdelta[A_CHUNK];
    int tid = threadIdx.x;
    for (int i = tid; i < 512; i += 256) lh[i] = 0;
    __syncthreads();

    int base = blockIdx.x * A_CHUNK;
    int dcache[A_CHUNK / 256];
    int scache[A_CHUNK / 256];
#pragma unroll
    for (int i = 0; i < A_CHUNK / 256; ++i) {
        int t = base + i * 256 + tid;
        int d = -1, s = 0;
        if (t < E) {
            d = __builtin_nontemporal_load(&dst[t]);
            s = __builtin_nontemporal_load(&src[t]);
            atomicAdd(&lh[d >> BKT_SHIFT], 1);
        }
        dcache[i] = d;
        scache[i] = s;
    }
    __syncthreads();

    // scan lh (512 entries, ping-pong Hillis-Steele) -> inclusive in psrc
    for (int i = tid; i < 512; i += 256) sA[i] = lh[i];
    __syncthreads();
    int* psrc = sA; int* pdst = sB;
    for (int off = 1; off < 512; off <<= 1) {
        for (int i = tid; i < 512; i += 256)
            pdst[i] = psrc[i] + ((i >= off) ? psrc[i - off] : 0);
        __syncthreads();
        int* tmp = psrc; psrc = pdst; pdst = tmp;
    }
    for (int i = tid; i < 512; i += 256) {
        int ex = psrc[i] - lh[i];
        lbase[i] = ex;
        lcur[i] = ex;
    }
    __syncthreads();

    // reserve one global segment per bucket for this chunk
    for (int b = tid; b < NB; b += 256) {
        int c = lh[b];
        int g = c ? atomicAdd(&bucket_cursor[b], c) : 0;
        sdelta[b] = g - lbase[b];
    }
    __syncthreads();

    // local reorder into rbuf
#pragma unroll
    for (int i = 0; i < A_CHUNK / 256; ++i) {
        int d = dcache[i];
        if (d >= 0) {
            int b = d >> BKT_SHIFT;
            int p = atomicAdd(&lcur[b], 1);
            rbuf[p] = (unsigned int)scache[i] | ((unsigned int)(d & 255) << PK_SHIFT);
            rdelta[p] = sdelta[b];
        }
    }
    __syncthreads();

    // write out: positions p within a segment map to consecutive global addresses
    int total = min(A_CHUNK, E - base);
    for (int p = tid; p < total; p += 256)
        binned[rdelta[p] + p] = rbuf[p];
}

// ---- pass B: per-bucket local counting sort -> adj, row_ptr/row_end/dinv ----
__global__ __launch_bounds__(256) void csr_kernel(const unsigned int* __restrict__ binned,
                                                  const int* __restrict__ bucket_base,
                                                  int* __restrict__ row_ptr,
                                                  int* __restrict__ row_end,
                                                  float* __restrict__ dinv,
                                                  int* __restrict__ adj, int n) {
    __shared__ int lh[256], lscan[256], lcur[256];
    __shared__ unsigned int rbuf[B_CAP];
    int b = blockIdx.x;
    int tid = threadIdx.x;
    int gbase = bucket_base[b];
    int gend  = bucket_base[b + 1];
    int m = gend - gbase;
    lh[tid] = 0;
    __syncthreads();
    // hist + LDS stage (nt loads: streaming, don't evict adj dirty lines)
    for (int i = tid; i < m; i += 256) {
        unsigned int w = __builtin_nontemporal_load(&binned[gbase + i]);
        if (i < B_CAP) rbuf[i] = w;
        atomicAdd(&lh[w >> PK_SHIFT], 1);
    }
    __syncthreads();
    // 256-entry Hillis-Steele scan
    int v = lh[tid];
    lscan[tid] = v;
    __syncthreads();
    for (int off = 1; off < 256; off <<= 1) {
        int t = (tid >= off) ? lscan[tid - off] : 0;
        __syncthreads();
        lscan[tid] += t;
        __syncthreads();
    }
    int ex = lscan[tid] - v;  // exclusive
    int node = (b << BKT_SHIFT) + tid;
    if (node < n) {
        row_ptr[node] = gbase + ex;
        row_end[node] = gbase + ex + v;
        dinv[node] = rsqrtf((float)v + 1.0f);
    }
    lcur[tid] = ex;
    __syncthreads();
    // scatter into this bucket's private 32KB adj window (L2 merges the fills)
    for (int i = tid; i < m; i += 256) {
        unsigned int w = (i < B_CAP) ? rbuf[i] : binned[gbase + i];
        int d = (int)(w >> PK_SHIFT);
        int s = (int)(w & PK_MASK);
        int p = atomicAdd(&lcur[d], 1);
        adj[gbase + p] = s;
    }
}

// ---- layer-1 matmul: h1s = (x @ W1) * dinv[node] ----
// One wave = one node per iteration; W1 register-resident per lane (K-slice
// {4l..4l+3} u {256+4l..+3}); two dense dwordx4 loads per node; feature-
// splitting butterfly leaves feature f in lane f. (round-4 verified, 192->~50us)
__global__ __launch_bounds__(256, 2) void mm1_kernel(const float* __restrict__ x,
                                                     const float* __restrict__ W1,
                                                     const float* __restrict__ dinv,
                                                     float* __restrict__ h1s, int n) {
    int tid = threadIdx.x;
    int lane = tid & 63;
    int wid  = blockIdx.x * 4 + (tid >> 6);   // global wave id
    int nwaves = gridDim.x * 4;

    // preload W1 rows kA = 4*lane + r and kB = 256 + 4*lane + r (r=0..3)
    float wA[4][16], wB[4][16];
#pragma unroll
    for (int r = 0; r < 4; ++r) {
        const float4* ra = (const float4*)(W1 + (size_t)(4 * lane + r) * F1);
        const float4* rb = (const float4*)(W1 + (size_t)(256 + 4 * lane + r) * F1);
#pragma unroll
        for (int q = 0; q < 4; ++q) {
            float4 va = ra[q], vb = rb[q];
            wA[r][4 * q + 0] = va.x; wA[r][4 * q + 1] = va.y;
            wA[r][4 * q + 2] = va.z; wA[r][4 * q + 3] = va.w;
            wB[r][4 * q + 0] = vb.x; wB[r][4 * q + 1] = vb.y;
            wB[r][4 * q + 2] = vb.z; wB[r][4 * q + 3] = vb.w;
        }
    }

    int node = wid;
    if (node >= n) return;
    const float* xb = x + (size_t)node * D_IN;
    vf4 pA = *(const vf4*)(xb + 4 * lane);          // k = 4l..4l+3
    vf4 pB = *(const vf4*)(xb + 256 + 4 * lane);    // k = 256+4l..+3

    while (node < n) {
        vf4 xA = pA, xB = pB;
        int nx = node + nwaves;
        if (nx < n) {                                // prefetch next row (wave-uniform branch)
            const float* xn = x + (size_t)nx * D_IN;
            pA = *(const vf4*)(xn + 4 * lane);
            pB = *(const vf4*)(xn + 256 + 4 * lane);
        }
        float acc[16];
#pragma unroll
        for (int f = 0; f < 16; ++f) acc[f] = 0.f;
#pragma unroll
        for (int r = 0; r < 4; ++r) {
            float ea = xA[r], eb = xB[r];
#pragma unroll
            for (int f = 0; f < 16; ++f) {
                acc[f] += ea * wA[r][f];
                acc[f] += eb * wB[r][f];
            }
        }
        // butterfly: stage s splits features by bit s == lane bit s -> lane f holds feature f
        int h0 = lane & 1, h1 = lane & 2, h2 = lane & 4, h3 = lane & 8;
        float a[8];
#pragma unroll
        for (int j = 0; j < 8; ++j) {
            float keep = h0 ? acc[2 * j + 1] : acc[2 * j];
            float give = h0 ? acc[2 * j] : acc[2 * j + 1];
            a[j] = keep + __shfl_xor(give, 1);
        }
        float b[4];
#pragma unroll
        for (int j = 0; j < 4; ++j) {
            float keep = h1 ? a[2 * j + 1] : a[2 * j];
            float give = h1 ? a[2 * j] : a[2 * j + 1];
            b[j] = keep + __shfl_xor(give, 2);
        }
        float c[2];
#pragma unroll
        for (int j = 0; j < 2; ++j) {
            float keep = h2 ? b[2 * j + 1] : b[2 * j];
            float give = h2 ? b[2 * j] : b[2 * j + 1];
            c[j] = keep + __shfl_xor(give, 4);
        }
        float d = (h3 ? c[1] : c[0]) + __shfl_xor(h3 ? c[0] : c[1], 8);
        d += __shfl_xor(d, 16);
        d += __shfl_xor(d, 32);
        if (lane < 16) {
            float di = dinv[node];
            h1s[(size_t)node * F1 + lane] = d * di;   // 64B contiguous store
        }
        node = nx;
    }
}

// ---- layer-1 gather + fused finalize + FUSED mm2 ----
// 16 lanes/node = (e4 edge-slice 0..3) x (jq float4 feature-quarter 0..3).
// Each lane walks edges k = s+e4 step 4 (2-unrolled): serial gather chain /4
// vs the per-j scalar walk; gathers stay line-coalesced (4 jq-lanes cover one
// 64B h-row). e4-butterfly (xor 4,8 width 16) -> all lanes hold the full
// 4-feature sum. Then relu(dinv*(sum+self)+b1), 28 FMAs of W2 partials,
// jq-butterfly (xor 1,2) -> full 7-dot in every lane; lanes 0..7 store the
// 32B h2s row (stride 8, slot7=0) * dinv. Replaces agg1+mm2 and the acc1
// round-trip. h2s goes to the old acc1 slot: h1s is still being gathered!
__global__ __launch_bounds__(256) void agg1_kernel(const int* __restrict__ row_ptr,
                                                   const int* __restrict__ row_end,
                                                   const int* __restrict__ adj,
                                                   const float* __restrict__ h,
                                                   const float* __restrict__ dinv,
                                                   const float* __restrict__ b1,
                                                   const float* __restrict__ W2,
                                                   float* __restrict__ h2s, int n) {
    int t = blockIdx.x * 256 + threadIdx.x;
    int node = t >> 4;
    if (node >= n) return;
    int li = t & 15;
    int jq = li & 3;
    int e4 = li >> 2;
    int s = row_ptr[node], e = row_end[node];
    vf4 a0 = {0.f, 0.f, 0.f, 0.f}, a1 = {0.f, 0.f, 0.f, 0.f};
    int k = s + e4;
    for (; k + 4 < e; k += 8) {
        int s0 = adj[k], s1 = adj[k + 4];
        a0 += *(const vf4*)(h + (size_t)s0 * F1 + jq * 4);
        a1 += *(const vf4*)(h + (size_t)s1 * F1 + jq * 4);
    }
    if (k < e) a0 += *(const vf4*)(h + (size_t)adj[k] * F1 + jq * 4);
    vf4 sum = a0 + a1;
#pragma unroll
    for (int q = 0; q < 4; ++q) {
        sum[q] += __shfl_xor(sum[q], 4, 16);
        sum[q] += __shfl_xor(sum[q], 8, 16);
    }
    float di = dinv[node];
    vf4 self = *(const vf4*)(h + (size_t)node * F1 + jq * 4);
    float v0 = di * (sum[0] + self[0]) + b1[jq * 4 + 0]; v0 = v0 > 0.f ? v0 : 0.f;
    float v1 = di * (sum[1] + self[1]) + b1[jq * 4 + 1]; v1 = v1 > 0.f ? v1 : 0.f;
    float v2 = di * (sum[2] + self[2]) + b1[jq * 4 + 2]; v2 = v2 > 0.f ? v2 : 0.f;
    float v3 = di * (sum[3] + self[3]) + b1[jq * 4 + 3]; v3 = v3 > 0.f ? v3 : 0.f;
    // mm2 partials: this lane's 4 features x W2 rows jq*4..jq*4+3
    const float* w0 = W2 + (size_t)(jq * 4 + 0) * F2;
    const float* w1 = W2 + (size_t)(jq * 4 + 1) * F2;
    const float* w2 = W2 + (size_t)(jq * 4 + 2) * F2;
    const float* w3 = W2 + (size_t)(jq * 4 + 3) * F2;
    float p0 = v0 * w0[0] + v1 * w1[0] + v2 * w2[0] + v3 * w3[0];
    float p1 = v0 * w0[1] + v1 * w1[1] + v2 * w2[1] + v3 * w3[1];
    float p2 = v0 * w0[2] + v1 * w1[2] + v2 * w2[2] + v3 * w3[2];
    float p3 = v0 * w0[3] + v1 * w1[3] + v2 * w2[3] + v3 * w3[3];
    float p4 = v0 * w0[4] + v1 * w1[4] + v2 * w2[4] + v3 * w3[4];
    float p5 = v0 * w0[5] + v1 * w1[5] + v2 * w2[5] + v3 * w3[5];
    float p6 = v0 * w0[6] + v1 * w1[6] + v2 * w2[6] + v3 * w3[6];
    // reduce over jq (lane bits 0-1)
    p0 += __shfl_xor(p0, 1, 16); p0 += __shfl_xor(p0, 2, 16);
    p1 += __shfl_xor(p1, 1, 16); p1 += __shfl_xor(p1, 2, 16);
    p2 += __shfl_xor(p2, 1, 16); p2 += __shfl_xor(p2, 2, 16);
    p3 += __shfl_xor(p3, 1, 16); p3 += __shfl_xor(p3, 2, 16);
    p4 += __shfl_xor(p4, 1, 16); p4 += __shfl_xor(p4, 2, 16);
    p5 += __shfl_xor(p5, 1, 16); p5 += __shfl_xor(p5, 2, 16);
    p6 += __shfl_xor(p6, 1, 16); p6 += __shfl_xor(p6, 2, 16);
    if (li < 8) {
        float oc = li == 0 ? p0 : li == 1 ? p1 : li == 2 ? p2 : li == 3 ? p3
                 : li == 4 ? p4 : li == 5 ? p5 : li == 6 ? p6 : 0.0f;
        h2s[(size_t)node * 8 + li] = oc * di;
    }
}

// ---- layer-2 gather + fused bias/self-loop/log_softmax -> out (stride 7) ----
// 8 lanes/node = (e4 edge-slice 0..3) x (jh half-row float4). Same edge-split
// as agg1: serial chain /4, 16B gathers (2 jh-lanes cover the 32B h2s row).
// e4-butterfly (xor 2,4 width 8) -> both jh lanes hold half-row sums; softmax
// over the 8 elems via one xor-1 exchange (slot7 = -INF pad).
__global__ __launch_bounds__(256) void agg2_kernel(const int* __restrict__ row_ptr,
                                                   const int* __restrict__ row_end,
                                                   const int* __restrict__ adj,
                                                   const float* __restrict__ h,
                                                   const float* __restrict__ dinv,
                                                   const float* __restrict__ b2,
                                                   float* __restrict__ out, int n) {
    int t = blockIdx.x * 256 + threadIdx.x;
    int node = t >> 3;
    if (node >= n) return;
    int li = t & 7;
    int jh = li & 1;
    int e4 = li >> 1;
    int s = row_ptr[node], e = row_end[node];
    vf4 a0 = {0.f, 0.f, 0.f, 0.f}, a1 = {0.f, 0.f, 0.f, 0.f};
    int k = s + e4;
    for (; k + 4 < e; k += 8) {
        int s0 = adj[k], s1 = adj[k + 4];
        a0 += *(const vf4*)(h + (size_t)s0 * 8 + jh * 4);
        a1 += *(const vf4*)(h + (size_t)s1 * 8 + jh * 4);
    }
    if (k < e) a0 += *(const vf4*)(h + (size_t)adj[k] * 8 + jh * 4);
    vf4 sum = a0 + a1;
#pragma unroll
    for (int q = 0; q < 4; ++q) {
        sum[q] += __shfl_xor(sum[q], 2, 8);
        sum[q] += __shfl_xor(sum[q], 4, 8);
    }
    float di = dinv[node];
    vf4 self = *(const vf4*)(h + (size_t)node * 8 + jh * 4);
    float v0 = di * (sum[0] + self[0]) + (jh ? b2[4] : b2[0]);
    float v1 = di * (sum[1] + self[1]) + (jh ? b2[5] : b2[1]);
    float v2 = di * (sum[2] + self[2]) + (jh ? b2[6] : b2[2]);
    float v3 = jh ? -INFINITY : di * (sum[3] + self[3]) + b2[3];
    float m4 = fmaxf(fmaxf(v0, v1), fmaxf(v2, v3));
    float m = fmaxf(m4, __shfl_xor(m4, 1, 8));
    float es = expf(v0 - m) + expf(v1 - m) + expf(v2 - m) + (jh ? 0.f : expf(v3 - m));
    float ssum = es + __shfl_xor(es, 1, 8);
    float lse = m + logf(ssum);
    float* op = out + (size_t)node * F2 + jh * 4;
    op[0] = v0 - lse; op[1] = v1 - lse; op[2] = v2 - lse;
    if (!jh) op[3] = v3 - lse;
}

extern "C" void kernel_launch(void* const* d_in, const int* in_sizes, int n_in,
                              void* d_out, int out_size, void* d_ws, size_t ws_size,
                              hipStream_t stream) {
    const float* x  = (const float*)d_in[0];
    const int*   ei = (const int*)d_in[1];
    const float* W1 = (const float*)d_in[2];
    const float* b1 = (const float*)d_in[3];
    const float* W2 = (const float*)d_in[4];
    const float* b2 = (const float*)d_in[5];

    int n = in_sizes[0] / D_IN;
    int E = in_sizes[1] / 2;
    const int* src = ei;
    const int* dst = ei + E;
    int NB = (n + 255) >> BKT_SHIFT;   // buckets (<=512 for n<=131072)

    // workspace layout (4-byte elements); binned aliases h1s/h2s (dead before mm1)
    char* ws = (char*)d_ws;
    size_t o = 0;
    int* bucket_cnt    = (int*)(ws + o); o += 512 * 4;
    int* bucket_base   = (int*)(ws + o); o += 516 * 4;
    int* bucket_cursor = (int*)(ws + o); o += 512 * 4;
    int*   row_ptr = (int*)(ws + o);   o += (size_t)n * 4;
    int*   row_end = (int*)(ws + o);   o += (size_t)n * 4;
    float* dinv    = (float*)(ws + o); o += (size_t)n * 4;
    int*   adj     = (int*)(ws + o);   o += (size_t)E * 4;
    size_t uni = (size_t)E > (size_t)n * 32 ? (size_t)E : (size_t)n * 32;
    unsigned int* binned = (unsigned int*)(ws + o);
    float* h1s = (float*)(ws + o);                     // overwrites binned after csr pass
    float* h2s = (float*)(ws + o) + (size_t)n * F1;    // fused agg1 output (NOT aliasing h1s)
    o += uni * 4;
    float* out = (float*)d_out;

    const int B = 256;
    int GA = (E + A_CHUNK - 1) / A_CHUNK;

    hipMemsetAsync(bucket_cnt, 0, 512 * sizeof(int), stream);

    binhist_kernel<<<GA, B, 0, stream>>>(dst, bucket_cnt, E, NB);
    bucketscan_kernel<<<1, 512, 0, stream>>>(bucket_cnt, bucket_base, bucket_cursor, NB, E);
    bin_kernel<<<GA, B, 0, stream>>>(src, dst, bucket_cursor, binned, E, NB);
    csr_kernel<<<NB, B, 0, stream>>>(binned, bucket_base, row_ptr, row_end, dinv, adj, n);

    mm1_kernel<<<512, B, 0, stream>>>(x, W1, dinv, h1s, n);

    agg1_kernel<<<((size_t)n * F1 + B - 1) / B, B, 0, stream>>>(row_ptr, row_end, adj, h1s, dinv, b1, W2, h2s, n);

    agg2_kernel<<<((size_t)n * 8 + B - 1) / B, B, 0, stream>>>(row_ptr, row_end, adj, h2s, dinv, b2, out, n);
}